// Round 8
// baseline (507.312 us; speedup 1.0000x reference)
//
#include <hip/hip_runtime.h>

// GeometricModel: two hyperbolic layers, FULLY FUSED per layer.
// N=32768, D=H=1024, c=1. fp32 in/out, bf16 MFMA internals, fp32 accumulate.
//
// fused_layer<FIRST>: BM=64 x BN=1024(full rows) x BK=32, 8 waves (wave w = cols
// w*128..+128, all 64 rows), acc[4][8] f32x4. B (whole W K-slice, 64KB) ring-2 +
// A ring-2 (4KB each) in LDS (~145KB, 1 block/CU). One vmcnt(0)+lgkm+barrier per step.
// Layer1 A-path: fp32 x -> reg cvt -> ds_write (+ exact fp32 row-norm). Layer2: gld_lds bf16.
// Epilogue IN-KERNEL: mx stays fp32 in acc; row reductions via shfl + LDS; u overwrites acc.
// Eliminates cast_x + both epilogue kernels; mx (2x64MB/layer round-trips) never hits HBM.

typedef short short8 __attribute__((ext_vector_type(8)));
typedef unsigned short u16x8 __attribute__((ext_vector_type(8)));
typedef unsigned short u16x4 __attribute__((ext_vector_type(4)));
typedef float f32x4 __attribute__((ext_vector_type(4)));

#define MAXN (1.0f - 1e-5f)

__device__ __forceinline__ float bf2f(unsigned short u) {
    return __uint_as_float(((unsigned int)u) << 16);
}
__device__ __forceinline__ unsigned short f2bf(float f) {
    unsigned int u = __float_as_uint(f);
    u += 0x7FFFu + ((u >> 16) & 1u);   // RNE
    return (unsigned short)(u >> 16);
}
__device__ __forceinline__ float wave_sum(float v) {
#pragma unroll
    for (int m = 32; m > 0; m >>= 1) v += __shfl_xor(v, m, 64);
    return v;
}
// fast tanh: 1 - 2/(exp(2x)+1); saturates correctly for large |x| via exp->{0,inf}.
__device__ __forceinline__ float tanh_fast(float x) {
    float e = __expf(2.0f * x);
    return 1.0f - __fdividef(2.0f, e + 1.0f);
}
__device__ __forceinline__ float artanh_clip(float x) {
    x = fminf(fmaxf(x, -1.0f + 1e-7f), 1.0f - 1e-7f);
    return 0.5f * __logf(__fdividef(1.0f + x, 1.0f - x));
}

// async 16B global->LDS (LDS dest = wave-uniform base + lane*16)
__device__ __forceinline__ void gld_lds16(const unsigned short* g, unsigned short* l) {
    __builtin_amdgcn_global_load_lds(
        (const __attribute__((address_space(1))) unsigned int*)g,
        (__attribute__((address_space(3))) unsigned int*)l,
        16, 0, 0);
}

// ---- W1,W2 fp32 -> bf16 (merged, one launch) ----
__global__ __launch_bounds__(256) void cast_w_kernel(
    const float* __restrict__ W1, unsigned short* __restrict__ W1b,
    const float* __restrict__ W2, unsigned short* __restrict__ W2b, int n4each)
{
    int i = blockIdx.x * 256 + threadIdx.x;
    const float4* src;
    u16x4* dst;
    if (i < n4each) { src = (const float4*)W1; dst = (u16x4*)W1b; }
    else            { src = (const float4*)W2; dst = (u16x4*)W2b; i -= n4each; }
    float4 v = src[i];
    u16x4 o;
    o[0] = f2bf(v.x); o[1] = f2bf(v.y); o[2] = f2bf(v.z); o[3] = f2bf(v.w);
    dst[i] = o;
}

// ---------------- fused layer ----------------
// FIRST=1: A = fp32 x, out = bf16 h (to ws) + xn_out.  FIRST=0: A = bf16 h, out = fp32.
template <int FIRST>
__global__ __launch_bounds__(512, 1) void fused_layer_kernel(
    const float* __restrict__ Af,
    const unsigned short* __restrict__ Ah,
    const unsigned short* __restrict__ B,     // bf16 W [Nc][K]
    const float* __restrict__ bvec,           // fp32 [Nc]
    const float* __restrict__ xn_in,          // used if !FIRST
    void* __restrict__ outp,
    float* __restrict__ xn_out,               // written if FIRST
    int K, int Nc)
{
    // LDS: B ring-2 (2x64KB) + A ring-2 (2x4KB) + reduction scratch (~5.5KB) = ~145KB
    __shared__ __align__(16) unsigned short sB[2][1024 * 32];
    __shared__ __align__(16) unsigned short sA[2][64 * 32];
    __shared__ __align__(16) float sP1[64 * 8];
    __shared__ __align__(16) float sP2[64 * 8];
    __shared__ __align__(16) float sF[64 * 4];
    __shared__ __align__(16) float sXN[64];

    const int t = threadIdx.x;       // 0..511
    const int l = t & 63;
    const int w = t >> 6;            // 0..7
    const int lr = l & 15;
    const int lq = l >> 4;
    const int g0 = blockIdx.x * 64;  // global row base (rows unique per block)
    const int wn = w * 128;          // this wave's col base

    // B staging: tile = Nc rows x 64B = 4096 chunks of 16B; thread handles 8 chunks.
    // phys chunk (row,s) holds logical slot s ^ ((row>>1)&3) -> pre-swizzled source.
    size_t gaB[8];
    int ldB[8];
#pragma unroll
    for (int j = 0; j < 8; ++j) {
        int c = t + 512 * j;
        int r = c >> 2, s = (c & 3) ^ ((r >> 1) & 3);
        gaB[j] = (size_t)r * K + s * 8;
        ldB[j] = c * 8;
    }
    // A staging (threads < 256): chunk c=t -> row t>>2, phys slot t&3
    const int rA = t >> 2;
    const int sAs = (t & 3) ^ ((rA >> 1) & 3);
    const size_t gaA = (size_t)(g0 + rA) * K + sAs * 8;

    // read-side swizzled 16B slot
    const int swo = (lq ^ ((lr >> 1) & 3)) * 8;

    f32x4 acc[4][8];
#pragma unroll
    for (int m = 0; m < 4; ++m)
#pragma unroll
        for (int n = 0; n < 8; ++n)
            acc[m][n] = (f32x4){0.f, 0.f, 0.f, 0.f};

    float ss = 0.f;   // FIRST: exact fp32 row-norm partial (this thread's col slice)

    auto stage = [&](int buf, int kt) {
#pragma unroll
        for (int j = 0; j < 8; ++j)
            gld_lds16(B + gaB[j] + kt * 32, &sB[buf][ldB[j]]);
        if (t < 256) {
            if constexpr (FIRST) {
                float4 v0 = *(const float4*)(Af + gaA + kt * 32);
                float4 v1 = *(const float4*)(Af + gaA + kt * 32 + 4);
                ss += v0.x * v0.x + v0.y * v0.y + v0.z * v0.z + v0.w * v0.w;
                ss += v1.x * v1.x + v1.y * v1.y + v1.z * v1.z + v1.w * v1.w;
                u16x8 o;
                o[0] = f2bf(v0.x); o[1] = f2bf(v0.y); o[2] = f2bf(v0.z); o[3] = f2bf(v0.w);
                o[4] = f2bf(v1.x); o[5] = f2bf(v1.y); o[6] = f2bf(v1.z); o[7] = f2bf(v1.w);
                *(u16x8*)&sA[buf][t * 8] = o;
            } else {
                gld_lds16(Ah + gaA + kt * 32, &sA[buf][t * 8]);
            }
        }
    };

    // prologue
    stage(0, 0);
    asm volatile("s_waitcnt vmcnt(0) lgkmcnt(0)" ::: "memory");
    __builtin_amdgcn_s_barrier();

    const int NTK = K >> 5;          // 32
#pragma unroll 1
    for (int kt = 0; kt < NTK; ++kt) {
        const int buf = kt & 1;
        if (kt + 1 < NTK) stage(buf ^ 1, kt + 1);
        short8 a[4], b[8];
#pragma unroll
        for (int m = 0; m < 4; ++m)
            a[m] = *(const short8*)&sA[buf][(m * 16 + lr) * 32 + swo];
#pragma unroll
        for (int n = 0; n < 8; ++n)
            b[n] = *(const short8*)&sB[buf][(wn + n * 16 + lr) * 32 + swo];
        __builtin_amdgcn_s_setprio(1);
#pragma unroll
        for (int m = 0; m < 4; ++m)
#pragma unroll
            for (int n = 0; n < 8; ++n)
                acc[m][n] = __builtin_amdgcn_mfma_f32_16x16x32_bf16(a[m], b[n], acc[m][n], 0, 0, 0);
        __builtin_amdgcn_s_setprio(0);
        asm volatile("s_waitcnt vmcnt(0) lgkmcnt(0)" ::: "memory");
        __builtin_amdgcn_s_barrier();
    }

    // ---------- fused hyperbolic epilogue ----------
    // acc layout (m89): col = wn + n*16 + lr; row = m*16 + lq*4 + r.

    // E0 (FIRST): finalize fp32 row norms from staging-thread partials
    if constexpr (FIRST) {
        if (t < 256) {
            float s2 = ss;
            s2 += __shfl_xor(s2, 1, 64);
            s2 += __shfl_xor(s2, 2, 64);
            if ((t & 3) == 0) sXN[t >> 2] = fmaxf(sqrtf(s2), 1e-15f);
        }
    }

    // E1: per-lane partial ssm / dmb over this wave's 8 col-tiles
    float bn_[8];
#pragma unroll
    for (int n = 0; n < 8; ++n) bn_[n] = bvec[wn + n * 16 + lr];

    float pm[4][4], pd[4][4];
#pragma unroll
    for (int m = 0; m < 4; ++m)
#pragma unroll
        for (int r = 0; r < 4; ++r) {
            float sm = 0.f, sd = 0.f;
#pragma unroll
            for (int n = 0; n < 8; ++n) {
                float v = acc[m][n][r];
                sm += v * v;
                sd += v * bn_[n];
            }
            pm[m][r] = sm; pd[m][r] = sd;
        }
#pragma unroll
    for (int mask = 1; mask <= 8; mask <<= 1)
#pragma unroll
        for (int m = 0; m < 4; ++m)
#pragma unroll
            for (int r = 0; r < 4; ++r) {
                pm[m][r] += __shfl_xor(pm[m][r], mask, 64);
                pd[m][r] += __shfl_xor(pd[m][r], mask, 64);
            }
    if (lr == 0) {
#pragma unroll
        for (int m = 0; m < 4; ++m)
#pragma unroll
            for (int r = 0; r < 4; ++r) {
                int row = m * 16 + lq * 4 + r;
                sP1[row * 8 + w] = pm[m][r];
                sP2[row * 8 + w] = pd[m][r];
            }
    }
    __syncthreads();

    // E2: per-row scalar chain (row = lane l; all waves redundant, wave 0 writes)
    float ssm = 0.f, dmb = 0.f;
#pragma unroll
    for (int j = 0; j < 8; ++j) { ssm += sP1[l * 8 + j]; dmb += sP2[l * 8 + j]; }
    float ssb = 0.f;
#pragma unroll
    for (int j = 0; j < 16; ++j) { float bj = bvec[l + 64 * j]; ssb += bj * bj; }
    ssb = wave_sum(ssb);

    float xn = FIRST ? sXN[l] : fmaxf(xn_in[g0 + l], 1e-15f);
    float mxn = fmaxf(sqrtf(ssm), 1e-15f);
    float bnn = fmaxf(sqrtf(ssb), 1e-15f);

    // gyro_matvec tail + proj
    float tt = tanh_fast(__fdividef(mxn, xn) * artanh_clip(xn));
    float rnorm = fabsf(tt);
    float pr = (rnorm > MAXN) ? __fdividef(MAXN, rnorm) : 1.0f;
    float resScale = __fdividef(tt * pr, mxn);
    float rn = fminf(rnorm, MAXN);
    float x2 = rn * rn;
    // hyp_bias = proj(expmap0(b))
    float tb = tanh_fast(bnn);
    float hbn = fabsf(tb);
    float pb = (hbn > MAXN) ? __fdividef(MAXN, hbn) : 1.0f;
    float hscale = __fdividef(tb, bnn) * pb;
    float hn = fminf(hbn, MAXN);
    float y2 = hn * hn;
    // gyro_add coefficients
    float xy = resScale * hscale * dmb;
    float ca = 1.0f + 2.0f * xy + y2;
    float cb = 1.0f - x2;
    float den = fmaxf(1.0f + 2.0f * xy + x2 * y2, 1e-15f);
    float fA = __fdividef(ca * resScale, den);
    float fB = __fdividef(cb * hscale, den);
    // ||z||^2 analytic, logmap0 scale incl. proj
    float ssz = fA * fA * ssm + 2.0f * fA * fB * dmb + fB * fB * ssb;
    float zn = fmaxf(sqrtf(fmaxf(ssz, 0.0f)), 1e-15f);
    float pz = (zn > MAXN) ? __fdividef(MAXN, zn) : 1.0f;
    float n2 = fmaxf(fminf(zn, MAXN), 1e-15f);
    float g = __fdividef(artanh_clip(n2), n2) * pz;

    if (w == 0) {
        float4 f4; f4.x = fA; f4.y = fB; f4.z = g; f4.w = 0.f;
        *(float4*)&sF[l * 4] = f4;
    }
    __syncthreads();

    // E3: u = tanh(g*(fA*m + fB*b)) overwrites acc; partial ssu
    float pu[4][4];
#pragma unroll
    for (int m = 0; m < 4; ++m)
#pragma unroll
        for (int r = 0; r < 4; ++r) {
            int row = m * 16 + lq * 4 + r;
            float4 f = *(const float4*)&sF[row * 4];   // broadcast within lr-group
            float su = 0.f;
#pragma unroll
            for (int n = 0; n < 8; ++n) {
                float z = f.x * acc[m][n][r] + f.y * bn_[n];
                float u = tanh_fast(f.z * z);
                acc[m][n][r] = u;
                su += u * u;
            }
            pu[m][r] = su;
        }
#pragma unroll
    for (int mask = 1; mask <= 8; mask <<= 1)
#pragma unroll
        for (int m = 0; m < 4; ++m)
#pragma unroll
            for (int r = 0; r < 4; ++r)
                pu[m][r] += __shfl_xor(pu[m][r], mask, 64);
    if (lr == 0) {
#pragma unroll
        for (int m = 0; m < 4; ++m)
#pragma unroll
            for (int r = 0; r < 4; ++r)
                sP1[(m * 16 + lq * 4 + r) * 8 + w] = pu[m][r];
    }
    __syncthreads();

    // E4: per-row expmap0 + proj scale (row = lane l)
    float ssu = 0.f;
#pragma unroll
    for (int j = 0; j < 8; ++j) ssu += sP1[l * 8 + j];
    float un = fmaxf(sqrtf(ssu), 1e-15f);
    float te = tanh_fast(un);
    float on = fabsf(te);
    float po = (on > MAXN) ? __fdividef(MAXN, on) : 1.0f;
    float os = __fdividef(te, un) * po;
    if (w == 0) {
        sXN[l] = os;   // reuse sXN as per-row output scale
        if constexpr (FIRST)
            xn_out[g0 + l] = fmaxf(fminf(on, MAXN), 1e-15f);   // analytic next-layer norm
    }
    __syncthreads();

    // E5: scaled write
#pragma unroll
    for (int m = 0; m < 4; ++m)
#pragma unroll
        for (int r = 0; r < 4; ++r) {
            int row = m * 16 + lq * 4 + r;
            float osr = sXN[row];
            if constexpr (FIRST) {
                unsigned short* op = (unsigned short*)outp + (size_t)(g0 + row) * Nc + wn + lr;
#pragma unroll
                for (int n = 0; n < 8; ++n) op[n * 16] = f2bf(osr * acc[m][n][r]);
            } else {
                float* op = (float*)outp + (size_t)(g0 + row) * Nc + wn + lr;
#pragma unroll
                for (int n = 0; n < 8; ++n) op[n * 16] = osr * acc[m][n][r];
            }
        }
}

extern "C" void kernel_launch(void* const* d_in, const int* in_sizes, int n_in,
                              void* d_out, int out_size, void* d_ws, size_t ws_size,
                              hipStream_t stream)
{
    const float* x  = (const float*)d_in[0];
    const float* W1 = (const float*)d_in[1];
    const float* b1 = (const float*)d_in[2];
    const float* W2 = (const float*)d_in[3];
    const float* b2 = (const float*)d_in[4];

    const int H = in_sizes[2];       // 1024
    const int D = in_sizes[1] / H;   // 1024
    const int N = in_sizes[0] / D;   // 32768

    // ws: h bf16 [N*H] (64MB) | W1b (2MB) | W2b (2MB) | xn2 (128KB)
    unsigned short* hb  = (unsigned short*)d_ws;
    unsigned short* W1b = hb + (size_t)N * H;
    unsigned short* W2b = W1b + (size_t)H * D;
    float* xn2 = (float*)(W2b + (size_t)H * H);
    float* outf = (float*)d_out;

    const int n4w = H * D / 4;
    cast_w_kernel<<<(2 * n4w + 255) / 256, dim3(256), 0, stream>>>(W1, W1b, W2, W2b, n4w);
    // layer 1: x fp32 -> h bf16 (ws) + xn2
    fused_layer_kernel<1><<<N / 64, dim3(512), 0, stream>>>(
        x, nullptr, W1b, b1, nullptr, hb, xn2, D, H);
    // layer 2: h bf16 -> final fp32 out
    fused_layer_kernel<0><<<N / 64, dim3(512), 0, stream>>>(
        nullptr, hb, W2b, b2, xn2, outf, nullptr, H, H);
}